// Round 8
// baseline (367.850 us; speedup 1.0000x reference)
//
#include <hip/hip_runtime.h>

typedef __attribute__((ext_vector_type(8))) short bf16x8;
typedef __attribute__((ext_vector_type(4))) float f32x4;
typedef __attribute__((ext_vector_type(16))) float f32x16;
typedef __attribute__((ext_vector_type(8))) unsigned short u16x8;
typedef __attribute__((ext_vector_type(4))) unsigned short u16x4;
typedef __attribute__((ext_vector_type(2))) unsigned int uint2v;

#define MFMA_16x16x32(a, b, c) __builtin_amdgcn_mfma_f32_16x16x32_bf16((a), (b), (c), 0, 0, 0)
#define MFMA32(a, b, c) __builtin_amdgcn_mfma_f32_32x32x16_bf16((a), (b), (c), 0, 0, 0)

__device__ __forceinline__ unsigned short f2bf(float f) {
  unsigned u = __builtin_bit_cast(unsigned, f);
  u += 0x7fffu + ((u >> 16) & 1u);   // round-to-nearest-even
  return (unsigned short)(u >> 16);
}

__device__ __forceinline__ void gload_lds16(const void* g, void* l) {
  __builtin_amdgcn_global_load_lds((__attribute__((address_space(1))) void*)(g),
                                   (__attribute__((address_space(3))) void*)(l),
                                   16, 0, 0);
}

__device__ __forceinline__ unsigned cvtpk(float lo, float hi) {
  unsigned r;
  asm("v_cvt_pk_bf16_f32 %0, %1, %2" : "=v"(r) : "v"(lo), "v"(hi));
  return r;
}

// ---------------------------------------------------------------- convert ---
__global__ void cvt_bf16(const float* __restrict__ src, unsigned short* __restrict__ dst, int n4) {
  int i = blockIdx.x * blockDim.x + threadIdx.x;
  if (i >= n4) return;
  f32x4 v = *(const f32x4*)(src + (size_t)i * 4);
  u16x4 o;
  o.x = f2bf(v.x); o.y = f2bf(v.y); o.z = f2bf(v.z); o.w = f2bf(v.w);
  *(u16x4*)(dst + (size_t)i * 4) = o;
}

// 4 weights in one launch (blockIdx.y selects)
__global__ void cvt_w4(const float* __restrict__ s0, const float* __restrict__ s1,
                       const float* __restrict__ s2, const float* __restrict__ s3,
                       unsigned short* __restrict__ d0, unsigned short* __restrict__ d1,
                       unsigned short* __restrict__ d2, unsigned short* __restrict__ d3,
                       int n4) {
  const float* s; unsigned short* d;
  switch (blockIdx.y) {
    case 0: s = s0; d = d0; break;
    case 1: s = s1; d = d1; break;
    case 2: s = s2; d = d2; break;
    default: s = s3; d = d3; break;
  }
  int i = blockIdx.x * blockDim.x + threadIdx.x;
  if (i >= n4) return;
  f32x4 v = *(const f32x4*)(s + (size_t)i * 4);
  u16x4 o;
  o.x = f2bf(v.x); o.y = f2bf(v.y); o.z = f2bf(v.z); o.w = f2bf(v.w);
  *(u16x4*)(d + (size_t)i * 4) = o;
}

// ------------------------------------------------------------------- GEMM ---
// C[M,N] = A[M,K] * B[N,K]^T, M=4096, N=K=1024.
// outmode 0: bf16 [M][N] scaled; 1: bf16 V-transpose Vt[(bh*64+d)*2048+s]; 2: fp32
template <int OUTMODE>
__device__ __forceinline__ void gemm_body(const unsigned short* __restrict__ A,
                                          const unsigned short* __restrict__ Bw,
                                          void* __restrict__ Cout, float scale,
                                          int bx, int by) {
  constexpr int K = 1024, N = 1024;
  __shared__ unsigned short As[128 * 32];
  __shared__ unsigned short Bs[128 * 32];
  const int tid = threadIdx.x;
  const int lane = tid & 63;
  const int wave = tid >> 6;
  const int wm = (wave >> 1) * 64;
  const int wn = (wave & 1) * 64;
  const int l15 = lane & 15, lg = lane >> 4;

  f32x4 acc[4][4];
#pragma unroll
  for (int mi = 0; mi < 4; ++mi)
#pragma unroll
    for (int ni = 0; ni < 4; ++ni) acc[mi][ni] = (f32x4){0.f, 0.f, 0.f, 0.f};

  const int r0 = tid >> 2;
  const int c0 = (tid & 3) * 8;
  const unsigned short* Ag = A + (size_t)(by * 128 + r0) * K + c0;
  const unsigned short* Bg = Bw + (size_t)(bx * 128 + r0) * K + c0;
  unsigned short* lA = As + tid * 8;
  unsigned short* lB = Bs + tid * 8;

  for (int kt = 0; kt < K / 32; ++kt) {
    __syncthreads();
    gload_lds16(Ag + kt * 32, lA);
    gload_lds16(Ag + (size_t)64 * K + kt * 32, lA + 2048);
    gload_lds16(Bg + kt * 32, lB);
    gload_lds16(Bg + (size_t)64 * K + kt * 32, lB + 2048);
    __syncthreads();

    bf16x8 af[4], bf[4];
#pragma unroll
    for (int mi = 0; mi < 4; ++mi)
      af[mi] = *(const bf16x8*)&As[(wm + mi * 16 + l15) * 32 + lg * 8];
#pragma unroll
    for (int ni = 0; ni < 4; ++ni)
      bf[ni] = *(const bf16x8*)&Bs[(wn + ni * 16 + l15) * 32 + lg * 8];
#pragma unroll
    for (int mi = 0; mi < 4; ++mi)
#pragma unroll
      for (int ni = 0; ni < 4; ++ni)
        acc[mi][ni] = MFMA_16x16x32(af[mi], bf[ni], acc[mi][ni]);
  }

#pragma unroll
  for (int mi = 0; mi < 4; ++mi) {
    const int row = by * 128 + wm + mi * 16 + lg * 4;
#pragma unroll
    for (int ni = 0; ni < 4; ++ni) {
      const int col = bx * 128 + wn + ni * 16 + l15;
#pragma unroll
      for (int i = 0; i < 4; ++i) {
        float v = acc[mi][ni][i];
        if constexpr (OUTMODE == 0) {
          ((unsigned short*)Cout)[(size_t)(row + i) * N + col] = f2bf(v * scale);
        } else if constexpr (OUTMODE == 1) {
          const int m = row + i, n = col;
          ((unsigned short*)Cout)[(size_t)(((m >> 11) * 16 + (n >> 6)) * 64 + (n & 63)) * 2048 +
                                  (m & 2047)] = f2bf(v);
        } else {
          ((float*)Cout)[(size_t)(row + i) * N + col] = v;
        }
      }
    }
  }
}

// fused QKV: grid (8, 32, 3); z=0 -> Q (scaled by log2e/8), z=1 -> K, z=2 -> Vt
__global__ __launch_bounds__(256) void gemm_qkv(const unsigned short* __restrict__ A,
                                                const unsigned short* __restrict__ Wq,
                                                const unsigned short* __restrict__ Wk,
                                                const unsigned short* __restrict__ Wv,
                                                unsigned short* __restrict__ Qo,
                                                unsigned short* __restrict__ Ko,
                                                unsigned short* __restrict__ Vo) {
  const int z = blockIdx.z;
  if (z == 0)      gemm_body<0>(A, Wq, Qo, 0.18033688011112042f, blockIdx.x, blockIdx.y);
  else if (z == 1) gemm_body<0>(A, Wk, Ko, 1.0f, blockIdx.x, blockIdx.y);
  else             gemm_body<1>(A, Wv, Vo, 1.0f, blockIdx.x, blockIdx.y);
}

__global__ __launch_bounds__(256) void gemm_out(const unsigned short* __restrict__ A,
                                                const unsigned short* __restrict__ Bw,
                                                float* __restrict__ C) {
  gemm_body<2>(A, Bw, C, 1.0f, blockIdx.x, blockIdx.y);
}

// -------------------------------------------------------- flash attention ---
// Split-K flash attention. Grid: 2048 blocks x 256 thr (4 waves).
// Block owns one (q-tile of 32 rows, bh); each wave scans nt/4 contiguous
// K-tiles with register-double-buffered K/V fragment prefetch; partials
// (m, l, o) merged across waves via padded LDS.
// Q,K: [B,S,H*HD] bf16 (Q pre-scaled by log2e/8). Vt: [B,H,HD,S] bf16.

#define LOADT(KA, KB, VA, VB, tt)                                          \
  {                                                                        \
    const unsigned short* _kp = kbase + (size_t)(tt) * 65536;              \
    const unsigned short* _vp = vbase + (size_t)(tt) * 64;                 \
    _Pragma("unroll")                                                      \
    for (int c = 0; c < 4; ++c) {                                          \
      KA[c] = *(const bf16x8*)(_kp + 16 * c);                              \
      KB[c] = *(const bf16x8*)(_kp + 32768 + 16 * c);                      \
      VA[c] = *(const bf16x8*)(_vp + 16 * c);                              \
      VB[c] = *(const bf16x8*)(_vp + 65536 + 16 * c);                      \
    }                                                                      \
  }

#define COMPT(KA, KB, VA, VB, tt, MASKED)                                      \
  {                                                                            \
    const int _k0 = (tt) * 64;                                                 \
    __builtin_amdgcn_s_setprio(1);                                             \
    f32x16 _s0 = MFMA32(KA[0], qf[0], nbj);                                    \
    f32x16 _s1 = MFMA32(KB[0], qf[0], nbj);                                    \
    _s0 = MFMA32(KA[1], qf[1], _s0); _s1 = MFMA32(KB[1], qf[1], _s1);          \
    _s0 = MFMA32(KA[2], qf[2], _s0); _s1 = MFMA32(KB[2], qf[2], _s1);          \
    _s0 = MFMA32(KA[3], qf[3], _s0); _s1 = MFMA32(KB[3], qf[3], _s1);          \
    __builtin_amdgcn_s_setprio(0);                                             \
    if (MASKED) {                                                              \
      const int _qk = qg - _k0 - 4 * H;                                        \
      _Pragma("unroll")                                                        \
      for (int r = 0; r < 16; ++r) {                                           \
        const int _cr = (r & 3) + 8 * (r >> 2);                                \
        _s0[r] = (_cr > _qk) ? -1e30f : _s0[r];                                \
        _s1[r] = (_cr + 32 > _qk) ? -1e30f : _s1[r];                           \
      }                                                                        \
    }                                                                          \
    const float _vb0 = sl2 * (float)_k0;                                       \
    const float _vb1 = sl2 * (float)(_k0 + 32);                                \
    float _mx0 = _s0[0], _mx1 = _s1[0];                                        \
    _Pragma("unroll")                                                          \
    for (int r = 1; r < 16; ++r) { _mx0 = fmaxf(_mx0, _s0[r]); _mx1 = fmaxf(_mx1, _s1[r]); } \
    float _tmax = fmaxf(_mx0 - _vb0, _mx1 - _vb1);                             \
    _tmax = fmaxf(_tmax, __shfl_xor(_tmax, 32, 64));                           \
    const float _mnew = fmaxf(m, _tmax);                                       \
    const float _corr = __builtin_amdgcn_exp2f(m - _mnew);                     \
    m = _mnew;                                                                 \
    const float _e0 = _vb0 + _mnew, _e1 = _vb1 + _mnew;                        \
    f32x16 _pp0, _pp1;                                                         \
    _Pragma("unroll")                                                          \
    for (int r = 0; r < 16; ++r) {                                             \
      _pp0[r] = __builtin_amdgcn_exp2f(_s0[r] - _e0);                          \
      _pp1[r] = __builtin_amdgcn_exp2f(_s1[r] - _e1);                          \
    }                                                                          \
    float _t8[8];                                                              \
    _Pragma("unroll")                                                          \
    for (int r = 0; r < 8; ++r) _t8[r] = (_pp0[r] + _pp0[r + 8]) + (_pp1[r] + _pp1[r + 8]); \
    float _tsum = ((_t8[0] + _t8[1]) + (_t8[2] + _t8[3])) + ((_t8[4] + _t8[5]) + (_t8[6] + _t8[7])); \
    _tsum += __shfl_xor(_tsum, 32, 64);                                        \
    l = l * _corr + _tsum;                                                     \
    _Pragma("unroll")                                                          \
    for (int r = 0; r < 16; ++r) { o0[r] *= _corr; o1[r] *= _corr; }           \
    _Pragma("unroll")                                                          \
    for (int ck = 0; ck < 4; ++ck) {                                           \
      const int _c = ck & 1;                                                   \
      unsigned _w0, _w1, _w2, _w3;                                             \
      if (ck < 2) {                                                            \
        _w0 = cvtpk(_pp0[8 * _c + 0], _pp0[8 * _c + 1]);                       \
        _w1 = cvtpk(_pp0[8 * _c + 2], _pp0[8 * _c + 3]);                       \
        _w2 = cvtpk(_pp0[8 * _c + 4], _pp0[8 * _c + 5]);                       \
        _w3 = cvtpk(_pp0[8 * _c + 6], _pp0[8 * _c + 7]);                       \
      } else {                                                                 \
        _w0 = cvtpk(_pp1[8 * _c + 0], _pp1[8 * _c + 1]);                       \
        _w1 = cvtpk(_pp1[8 * _c + 2], _pp1[8 * _c + 3]);                       \
        _w2 = cvtpk(_pp1[8 * _c + 4], _pp1[8 * _c + 5]);                       \
        _w3 = cvtpk(_pp1[8 * _c + 6], _pp1[8 * _c + 7]);                       \
      }                                                                        \
      unsigned _sa = H ? _w0 : _w2;                                            \
      unsigned _sb = H ? _w1 : _w3;                                            \
      _sa = (unsigned)__shfl_xor((int)_sa, 32, 64);                            \
      _sb = (unsigned)__shfl_xor((int)_sb, 32, 64);                            \
      union { unsigned u[4]; bf16x8 v; } _fr;                                  \
      _fr.u[0] = H ? _sa : _w0;                                                \
      _fr.u[1] = H ? _sb : _w1;                                                \
      _fr.u[2] = H ? _w2 : _sa;                                                \
      _fr.u[3] = H ? _w3 : _sb;                                                \
      __builtin_amdgcn_s_setprio(1);                                           \
      o0 = MFMA32(VA[ck], _fr.v, o0);                                          \
      o1 = MFMA32(VB[ck], _fr.v, o1);                                          \
      __builtin_amdgcn_s_setprio(0);                                           \
    }                                                                          \
  }

__global__ __launch_bounds__(256, 2) void attn_fwd(const unsigned short* __restrict__ Qg,
                                                   const unsigned short* __restrict__ Kg,
                                                   const unsigned short* __restrict__ Vtg,
                                                   unsigned short* __restrict__ Og) {
  constexpr int S = 2048;
  __shared__ float Ml[4][64];
  __shared__ float Ll[4][64];
  __shared__ float Oacc[64][33];   // +1 pad word per 32 -> conflict-free

  // bid -> (xcd, qt heavy-first, bh): per-XCD head pinning + LPT order
  const int bid = blockIdx.x;           // [0, 2048)
  const int xcd = bid & 7;
  const int ord = bid >> 3;             // [0, 256)
  const int qt = 63 - (ord >> 2);       // heavy (diagonal) q-tiles first
  const int bh = xcd * 4 + (ord & 3);
  const int b = bh >> 4, h = bh & 15;

  const int lane = threadIdx.x & 63;
  const int wave = threadIdx.x >> 6;
  const int ql = lane & 31;
  const int H = lane >> 5;
  const int qg = qt * 32 + ql;          // q-row owned by this lane
  const float slope = exp2f(-0.5f * (float)(h + 1));
  const float sl2 = slope * 1.44269504088896f;   // slope * log2(e)

  // Q fragments (B-operand: lane holds col q, d = 16c + 8H + j)
  bf16x8 qf[4];
  {
    const unsigned short* qp = Qg + (size_t)(b * S + qg) * 1024 + h * 64 + H * 8;
#pragma unroll
    for (int c = 0; c < 4; ++c) qf[c] = *(const bf16x8*)(qp + 16 * c);
  }

  // -bias table as MFMA C-init: nbj[r] = -sl2 * (crow(r) + 4H)
  f32x16 nbj;
#pragma unroll
  for (int r = 0; r < 16; ++r) {
    const float crow = (float)((r & 3) + 8 * (r >> 2) + 4 * H);
    nbj[r] = -sl2 * crow;
  }

  const unsigned short* kbase = Kg + (size_t)(b * S + ql) * 1024 + h * 64 + H * 8;
  const unsigned short* vbase = Vtg + (size_t)(bh * 64 + ql) * S + H * 8;

  f32x16 o0, o1;
#pragma unroll
  for (int r = 0; r < 16; ++r) { o0[r] = 0.f; o1[r] = 0.f; }
  float m = -1e30f, l = 0.f;

  // per-wave contiguous K-chunk [t0, te) of the q-tile's nt tiles
  const int nt = (qt >> 1) + 1;
  const int cs = (nt + 3) >> 2;
  const int t0 = wave * cs;
  const int te = min(nt, t0 + cs);

  bf16x8 ka0[4], ka1[4], vA0[4], vA1[4];
  bf16x8 kb0[4], kb1[4], vB0[4], vB1[4];

  if (t0 < te) {
    LOADT(ka0, ka1, vA0, vA1, t0);
    int t = t0;
    for (; t + 1 < te; ++t) {
      if ((t - t0) & 1) {
        LOADT(ka0, ka1, vA0, vA1, t + 1);
        COMPT(kb0, kb1, vB0, vB1, t, false);
      } else {
        LOADT(kb0, kb1, vB0, vB1, t + 1);
        COMPT(ka0, ka1, vA0, vA1, t, false);
      }
    }
    const bool msk = (te == nt);        // global diagonal tile lives here
    if ((t - t0) & 1) {
      COMPT(kb0, kb1, vB0, vB1, t, msk);
    } else {
      COMPT(ka0, ka1, vA0, vA1, t, msk);
    }
  }

  // ---- cross-wave merge of (m, l, o) partials
  Ml[wave][lane] = m;
  Ll[wave][lane] = l;
  __syncthreads();
  const float M = fmaxf(fmaxf(Ml[0][lane], Ml[1][lane]), fmaxf(Ml[2][lane], Ml[3][lane]));
  const float ci = __builtin_amdgcn_exp2f(m - M);
  float lt = Ll[0][lane] * __builtin_amdgcn_exp2f(Ml[0][lane] - M);
  lt += Ll[1][lane] * __builtin_amdgcn_exp2f(Ml[1][lane] - M);
  lt += Ll[2][lane] * __builtin_amdgcn_exp2f(Ml[2][lane] - M);
  lt += Ll[3][lane] * __builtin_amdgcn_exp2f(Ml[3][lane] - M);
#pragma unroll
  for (int r = 0; r < 16; ++r) { o0[r] *= ci; o1[r] *= ci; }

  if (wave == 0) {
#pragma unroll
    for (int r = 0; r < 16; ++r) { Oacc[lane][r] = o0[r]; Oacc[lane][16 + r] = o1[r]; }
  }
  __syncthreads();
  if (wave == 1) {
#pragma unroll
    for (int r = 0; r < 16; ++r) { Oacc[lane][r] += o0[r]; Oacc[lane][16 + r] += o1[r]; }
  }
  __syncthreads();
  if (wave == 2) {
#pragma unroll
    for (int r = 0; r < 16; ++r) { Oacc[lane][r] += o0[r]; Oacc[lane][16 + r] += o1[r]; }
  }
  __syncthreads();
  if (wave == 3) {
#pragma unroll
    for (int r = 0; r < 16; ++r) { o0[r] += Oacc[lane][r]; o1[r] += Oacc[lane][16 + r]; }
    const float rl = 1.0f / lt;
    unsigned short* ob = Og + (size_t)(b * S + qg) * 1024 + h * 64 + 4 * H;
#pragma unroll
    for (int a2 = 0; a2 < 4; ++a2) {
      uint2v w01, w23;
      w01.x = cvtpk(o0[4 * a2 + 0] * rl, o0[4 * a2 + 1] * rl);
      w01.y = cvtpk(o0[4 * a2 + 2] * rl, o0[4 * a2 + 3] * rl);
      w23.x = cvtpk(o1[4 * a2 + 0] * rl, o1[4 * a2 + 1] * rl);
      w23.y = cvtpk(o1[4 * a2 + 2] * rl, o1[4 * a2 + 3] * rl);
      *(uint2v*)(ob + 8 * a2) = w01;
      *(uint2v*)(ob + 32 + 8 * a2) = w23;
    }
  }
}

// ----------------------------------------------------------------- launch ---
extern "C" void kernel_launch(void* const* d_in, const int* in_sizes, int n_in,
                              void* d_out, int out_size, void* d_ws, size_t ws_size,
                              hipStream_t stream) {
  const float* x = (const float*)d_in[0];
  const float* Wq = (const float*)d_in[1];
  const float* Wk = (const float*)d_in[2];
  const float* Wv = (const float*)d_in[3];
  const float* Wo = (const float*)d_in[4];

  unsigned short* xb = (unsigned short*)d_ws;          // 4194304
  unsigned short* Wqb = xb + 4194304;                  // 1048576 each
  unsigned short* Wkb = Wqb + 1048576;
  unsigned short* Wvb = Wkb + 1048576;
  unsigned short* Wob = Wvb + 1048576;
  unsigned short* Qb = Wob + 1048576;                  // 4194304 each
  unsigned short* Kb = Qb + 4194304;
  unsigned short* Vtb = Kb + 4194304;
  unsigned short* Ob = Vtb + 4194304;

  cvt_bf16<<<4096, 256, 0, stream>>>(x, xb, 1048576);
  cvt_w4<<<dim3(1024, 4), 256, 0, stream>>>(Wq, Wk, Wv, Wo, Wqb, Wkb, Wvb, Wob, 262144);

  gemm_qkv<<<dim3(8, 32, 3), 256, 0, stream>>>(xb, Wqb, Wkb, Wvb, Qb, Kb, Vtb);

  attn_fwd<<<2048, 256, 0, stream>>>(Qb, Kb, Vtb, Ob);

  gemm_out<<<dim3(8, 32), 256, 0, stream>>>(Ob, Wob, (float*)d_out);
}

// Round 9
// 193.389 us; speedup vs baseline: 1.9021x; 1.9021x over previous
//
#include <hip/hip_runtime.h>

typedef __attribute__((ext_vector_type(8))) short bf16x8;
typedef __attribute__((ext_vector_type(4))) float f32x4;
typedef __attribute__((ext_vector_type(16))) float f32x16;
typedef __attribute__((ext_vector_type(8))) unsigned short u16x8;
typedef __attribute__((ext_vector_type(4))) unsigned short u16x4;
typedef __attribute__((ext_vector_type(2))) unsigned int uint2v;

#define MFMA_16x16x32(a, b, c) __builtin_amdgcn_mfma_f32_16x16x32_bf16((a), (b), (c), 0, 0, 0)
#define MFMA32(a, b, c) __builtin_amdgcn_mfma_f32_32x32x16_bf16((a), (b), (c), 0, 0, 0)

__device__ __forceinline__ unsigned short f2bf(float f) {
  unsigned u = __builtin_bit_cast(unsigned, f);
  u += 0x7fffu + ((u >> 16) & 1u);   // round-to-nearest-even
  return (unsigned short)(u >> 16);
}

__device__ __forceinline__ void gload_lds16(const void* g, void* l) {
  __builtin_amdgcn_global_load_lds((__attribute__((address_space(1))) void*)(g),
                                   (__attribute__((address_space(3))) void*)(l),
                                   16, 0, 0);
}

__device__ __forceinline__ unsigned cvtpk(float lo, float hi) {
  unsigned r;
  asm("v_cvt_pk_bf16_f32 %0, %1, %2" : "=v"(r) : "v"(lo), "v"(hi));
  return r;
}

// ---------------------------------------------------------------- convert ---
__global__ void cvt_bf16(const float* __restrict__ src, unsigned short* __restrict__ dst, int n4) {
  int i = blockIdx.x * blockDim.x + threadIdx.x;
  if (i >= n4) return;
  f32x4 v = *(const f32x4*)(src + (size_t)i * 4);
  u16x4 o;
  o.x = f2bf(v.x); o.y = f2bf(v.y); o.z = f2bf(v.z); o.w = f2bf(v.w);
  *(u16x4*)(dst + (size_t)i * 4) = o;
}

// 4 weights in one launch (blockIdx.y selects)
__global__ void cvt_w4(const float* __restrict__ s0, const float* __restrict__ s1,
                       const float* __restrict__ s2, const float* __restrict__ s3,
                       unsigned short* __restrict__ d0, unsigned short* __restrict__ d1,
                       unsigned short* __restrict__ d2, unsigned short* __restrict__ d3,
                       int n4) {
  const float* s; unsigned short* d;
  switch (blockIdx.y) {
    case 0: s = s0; d = d0; break;
    case 1: s = s1; d = d1; break;
    case 2: s = s2; d = d2; break;
    default: s = s3; d = d3; break;
  }
  int i = blockIdx.x * blockDim.x + threadIdx.x;
  if (i >= n4) return;
  f32x4 v = *(const f32x4*)(s + (size_t)i * 4);
  u16x4 o;
  o.x = f2bf(v.x); o.y = f2bf(v.y); o.z = f2bf(v.z); o.w = f2bf(v.w);
  *(u16x4*)(d + (size_t)i * 4) = o;
}

// ------------------------------------------------------------------- GEMM ---
// C[M,N] = A[M,K] * B[N,K]^T, M=4096, N=K=1024.
// outmode 0: bf16 [M][N] scaled; 1: bf16 V-transpose Vt[(bh*64+d)*2048+s]; 2: fp32
template <int OUTMODE>
__device__ __forceinline__ void gemm_body(const unsigned short* __restrict__ A,
                                          const unsigned short* __restrict__ Bw,
                                          void* __restrict__ Cout, float scale,
                                          int bx, int by) {
  constexpr int K = 1024, N = 1024;
  __shared__ unsigned short As[128 * 32];
  __shared__ unsigned short Bs[128 * 32];
  const int tid = threadIdx.x;
  const int lane = tid & 63;
  const int wave = tid >> 6;
  const int wm = (wave >> 1) * 64;
  const int wn = (wave & 1) * 64;
  const int l15 = lane & 15, lg = lane >> 4;

  f32x4 acc[4][4];
#pragma unroll
  for (int mi = 0; mi < 4; ++mi)
#pragma unroll
    for (int ni = 0; ni < 4; ++ni) acc[mi][ni] = (f32x4){0.f, 0.f, 0.f, 0.f};

  const int r0 = tid >> 2;
  const int c0 = (tid & 3) * 8;
  const unsigned short* Ag = A + (size_t)(by * 128 + r0) * K + c0;
  const unsigned short* Bg = Bw + (size_t)(bx * 128 + r0) * K + c0;
  unsigned short* lA = As + tid * 8;
  unsigned short* lB = Bs + tid * 8;

  for (int kt = 0; kt < K / 32; ++kt) {
    __syncthreads();
    gload_lds16(Ag + kt * 32, lA);
    gload_lds16(Ag + (size_t)64 * K + kt * 32, lA + 2048);
    gload_lds16(Bg + kt * 32, lB);
    gload_lds16(Bg + (size_t)64 * K + kt * 32, lB + 2048);
    __syncthreads();

    bf16x8 af[4], bf[4];
#pragma unroll
    for (int mi = 0; mi < 4; ++mi)
      af[mi] = *(const bf16x8*)&As[(wm + mi * 16 + l15) * 32 + lg * 8];
#pragma unroll
    for (int ni = 0; ni < 4; ++ni)
      bf[ni] = *(const bf16x8*)&Bs[(wn + ni * 16 + l15) * 32 + lg * 8];
#pragma unroll
    for (int mi = 0; mi < 4; ++mi)
#pragma unroll
      for (int ni = 0; ni < 4; ++ni)
        acc[mi][ni] = MFMA_16x16x32(af[mi], bf[ni], acc[mi][ni]);
  }

#pragma unroll
  for (int mi = 0; mi < 4; ++mi) {
    const int row = by * 128 + wm + mi * 16 + lg * 4;
#pragma unroll
    for (int ni = 0; ni < 4; ++ni) {
      const int col = bx * 128 + wn + ni * 16 + l15;
#pragma unroll
      for (int i = 0; i < 4; ++i) {
        float v = acc[mi][ni][i];
        if constexpr (OUTMODE == 0) {
          ((unsigned short*)Cout)[(size_t)(row + i) * N + col] = f2bf(v * scale);
        } else if constexpr (OUTMODE == 1) {
          const int m = row + i, n = col;
          ((unsigned short*)Cout)[(size_t)(((m >> 11) * 16 + (n >> 6)) * 64 + (n & 63)) * 2048 +
                                  (m & 2047)] = f2bf(v);
        } else {
          ((float*)Cout)[(size_t)(row + i) * N + col] = v;
        }
      }
    }
  }
}

// fused QKV: grid (8, 32, 3); z=0 -> Q (scaled by log2e/8), z=1 -> K, z=2 -> Vt
__global__ __launch_bounds__(256) void gemm_qkv(const unsigned short* __restrict__ A,
                                                const unsigned short* __restrict__ Wq,
                                                const unsigned short* __restrict__ Wk,
                                                const unsigned short* __restrict__ Wv,
                                                unsigned short* __restrict__ Qo,
                                                unsigned short* __restrict__ Ko,
                                                unsigned short* __restrict__ Vo) {
  const int z = blockIdx.z;
  if (z == 0)      gemm_body<0>(A, Wq, Qo, 0.18033688011112042f, blockIdx.x, blockIdx.y);
  else if (z == 1) gemm_body<0>(A, Wk, Ko, 1.0f, blockIdx.x, blockIdx.y);
  else             gemm_body<1>(A, Wv, Vo, 1.0f, blockIdx.x, blockIdx.y);
}

__global__ __launch_bounds__(256) void gemm_out(const unsigned short* __restrict__ A,
                                                const unsigned short* __restrict__ Bw,
                                                float* __restrict__ C) {
  gemm_body<2>(A, Bw, C, 1.0f, blockIdx.x, blockIdx.y);
}

// -------------------------------------------------------- flash attention ---
// Block = 128 q-rows (4 waves x 32) of one (b,h); waves share LDS-staged K/V
// tiles (double-buffered, global_load_lds, both-sides XOR swizzle).
// Q,K: [B,S,H*HD] bf16 (Q pre-scaled by log2e/8). Vt: [B,H,HD,S] bf16.
// Numeric core identical to the verified Round-7 kernel.

// stage tile tt into buffer bsel: 4 gload_lds16/thread, coalesced 128B rows,
// global source pre-swizzled so swizzled LDS reads see linear data (rule #21)
#define STAGE(bsel, tt)                                                        \
  {                                                                            \
    const unsigned short* kS = Kg + (size_t)(bS + (tt) * 64 + rs) * 1024 + h64 + swoff; \
    const unsigned short* vS = Vtg + (size_t)(bh64 + rs) * 2048 + (tt) * 64 + swoff;    \
    unsigned short* kD = KsB + (bsel) * 4096 + wave * 512;                     \
    unsigned short* vD = VsB + (bsel) * 4096 + wave * 512;                     \
    gload_lds16(kS, kD);                                                       \
    gload_lds16(kS + 32 * 1024, kD + 2048);                                    \
    gload_lds16(vS, vD);                                                       \
    gload_lds16(vS + 32 * 2048, vD + 2048);                                    \
  }

#define COMPT(tt, MASKED)                                                      \
  {                                                                            \
    const unsigned short* Kc = KsB + cur * 4096;                               \
    const unsigned short* Vc = VsB + cur * 4096;                               \
    const int _k0 = (tt) * 64;                                                 \
    bf16x8 kf0[4], kf1[4];                                                     \
    _Pragma("unroll")                                                          \
    for (int c = 0; c < 4; ++c) {                                              \
      const int _off = ((32 * c + 16 * H) ^ ((ql & 7) << 4)) >> 1;             \
      kf0[c] = *(const bf16x8*)(Kc + ql * 64 + _off);                          \
      kf1[c] = *(const bf16x8*)(Kc + (ql + 32) * 64 + _off);                   \
    }                                                                          \
    __builtin_amdgcn_s_setprio(1);                                             \
    f32x16 _s0 = MFMA32(kf0[0], qf[0], nbj);                                   \
    f32x16 _s1 = MFMA32(kf1[0], qf[0], nbj);                                   \
    _s0 = MFMA32(kf0[1], qf[1], _s0); _s1 = MFMA32(kf1[1], qf[1], _s1);        \
    _s0 = MFMA32(kf0[2], qf[2], _s0); _s1 = MFMA32(kf1[2], qf[2], _s1);        \
    _s0 = MFMA32(kf0[3], qf[3], _s0); _s1 = MFMA32(kf1[3], qf[3], _s1);        \
    __builtin_amdgcn_s_setprio(0);                                             \
    if (MASKED) {                                                              \
      const int _qk = qg - _k0 - 4 * H;                                        \
      _Pragma("unroll")                                                        \
      for (int r = 0; r < 16; ++r) {                                           \
        const int _cr = (r & 3) + 8 * (r >> 2);                                \
        _s0[r] = (_cr > _qk) ? -1e30f : _s0[r];                                \
        _s1[r] = (_cr + 32 > _qk) ? -1e30f : _s1[r];                           \
      }                                                                        \
    }                                                                          \
    const float _vb0 = sl2 * (float)_k0;                                       \
    const float _vb1 = sl2 * (float)(_k0 + 32);                                \
    float _mx0 = _s0[0], _mx1 = _s1[0];                                        \
    _Pragma("unroll")                                                          \
    for (int r = 1; r < 16; ++r) { _mx0 = fmaxf(_mx0, _s0[r]); _mx1 = fmaxf(_mx1, _s1[r]); } \
    float _tmax = fmaxf(_mx0 - _vb0, _mx1 - _vb1);                             \
    _tmax = fmaxf(_tmax, __shfl_xor(_tmax, 32, 64));                           \
    const float _mnew = fmaxf(m, _tmax);                                       \
    const float _corr = __builtin_amdgcn_exp2f(m - _mnew);                     \
    m = _mnew;                                                                 \
    const float _e0 = _vb0 + _mnew, _e1 = _vb1 + _mnew;                        \
    f32x16 _pp0, _pp1;                                                         \
    _Pragma("unroll")                                                          \
    for (int r = 0; r < 16; ++r) {                                             \
      _pp0[r] = __builtin_amdgcn_exp2f(_s0[r] - _e0);                          \
      _pp1[r] = __builtin_amdgcn_exp2f(_s1[r] - _e1);                          \
    }                                                                          \
    float _t8[8];                                                              \
    _Pragma("unroll")                                                          \
    for (int r = 0; r < 8; ++r) _t8[r] = (_pp0[r] + _pp0[r + 8]) + (_pp1[r] + _pp1[r + 8]); \
    float _tsum = ((_t8[0] + _t8[1]) + (_t8[2] + _t8[3])) + ((_t8[4] + _t8[5]) + (_t8[6] + _t8[7])); \
    _tsum += __shfl_xor(_tsum, 32, 64);                                        \
    l = l * _corr + _tsum;                                                     \
    _Pragma("unroll")                                                          \
    for (int r = 0; r < 16; ++r) { o0[r] *= _corr; o1[r] *= _corr; }           \
    bf16x8 vf0[4], vf1[4];                                                     \
    _Pragma("unroll")                                                          \
    for (int c = 0; c < 4; ++c) {                                              \
      const int _off = ((32 * c + 16 * H) ^ ((ql & 7) << 4)) >> 1;             \
      vf0[c] = *(const bf16x8*)(Vc + ql * 64 + _off);                          \
      vf1[c] = *(const bf16x8*)(Vc + (ql + 32) * 64 + _off);                   \
    }                                                                          \
    _Pragma("unroll")                                                          \
    for (int ck = 0; ck < 4; ++ck) {                                           \
      const int _c = ck & 1;                                                   \
      unsigned _w0, _w1, _w2, _w3;                                             \
      if (ck < 2) {                                                            \
        _w0 = cvtpk(_pp0[8 * _c + 0], _pp0[8 * _c + 1]);                       \
        _w1 = cvtpk(_pp0[8 * _c + 2], _pp0[8 * _c + 3]);                       \
        _w2 = cvtpk(_pp0[8 * _c + 4], _pp0[8 * _c + 5]);                       \
        _w3 = cvtpk(_pp0[8 * _c + 6], _pp0[8 * _c + 7]);                       \
      } else {                                                                 \
        _w0 = cvtpk(_pp1[8 * _c + 0], _pp1[8 * _c + 1]);                       \
        _w1 = cvtpk(_pp1[8 * _c + 2], _pp1[8 * _c + 3]);                       \
        _w2 = cvtpk(_pp1[8 * _c + 4], _pp1[8 * _c + 5]);                       \
        _w3 = cvtpk(_pp1[8 * _c + 6], _pp1[8 * _c + 7]);                       \
      }                                                                        \
      unsigned _sa = H ? _w0 : _w2;                                            \
      unsigned _sb = H ? _w1 : _w3;                                            \
      _sa = (unsigned)__shfl_xor((int)_sa, 32, 64);                            \
      _sb = (unsigned)__shfl_xor((int)_sb, 32, 64);                            \
      union { unsigned u[4]; bf16x8 v; } _fr;                                  \
      _fr.u[0] = H ? _sa : _w0;                                                \
      _fr.u[1] = H ? _sb : _w1;                                                \
      _fr.u[2] = H ? _w2 : _sa;                                                \
      _fr.u[3] = H ? _w3 : _sb;                                                \
      __builtin_amdgcn_s_setprio(1);                                           \
      o0 = MFMA32(vf0[ck], _fr.v, o0);                                         \
      o1 = MFMA32(vf1[ck], _fr.v, o1);                                         \
      __builtin_amdgcn_s_setprio(0);                                           \
    }                                                                          \
  }

__global__ __launch_bounds__(256, 2) void attn_fwd(const unsigned short* __restrict__ Qg,
                                                   const unsigned short* __restrict__ Kg,
                                                   const unsigned short* __restrict__ Vtg,
                                                   unsigned short* __restrict__ Og) {
  constexpr int S = 2048;
  __shared__ unsigned short KsB[2 * 4096];   // 2 x (64 rows x 64 cols) bf16
  __shared__ unsigned short VsB[2 * 4096];

  // bid -> (xcd-pinned head, LPT heavy-first q-block)
  const int bid = blockIdx.x;           // [0, 512)
  const int xcd = bid & 7;
  const int idx = bid >> 3;             // [0, 64)
  const int qb = 15 - (idx >> 2);       // heavy (diagonal) q-blocks first
  const int bh = xcd * 4 + (idx & 3);
  const int b = bh >> 4, h = bh & 15;

  const int tid = threadIdx.x;
  const int lane = tid & 63;
  const int wave = tid >> 6;
  const int ql = lane & 31;
  const int H = lane >> 5;
  const int qw0 = qb * 128 + wave * 32;
  const int qg = qw0 + ql;              // q-row owned by this lane
  const float slope = exp2f(-0.5f * (float)(h + 1));
  const float sl2 = slope * 1.44269504088896f;   // slope * log2(e)

  const int bS = b * S;
  const int h64 = h * 64;
  const int bh64 = bh * 64;

  // Q fragments (B-operand: lane holds col q, d = 16c + 8H + j)
  bf16x8 qf[4];
  {
    const unsigned short* qp = Qg + (size_t)(bS + qg) * 1024 + h64 + H * 8;
#pragma unroll
    for (int c = 0; c < 4; ++c) qf[c] = *(const bf16x8*)(qp + 16 * c);
  }

  // -bias table as MFMA C-init: nbj[r] = -sl2 * (crow(r) + 4H)
  f32x16 nbj;
#pragma unroll
  for (int r = 0; r < 16; ++r) {
    const float crow = (float)((r & 3) + 8 * (r >> 2) + 4 * H);
    nbj[r] = -sl2 * crow;
  }

  f32x16 o0, o1;
#pragma unroll
  for (int r = 0; r < 16; ++r) { o0[r] = 0.f; o1[r] = 0.f; }
  float m = -1e30f, l = 0.f;

  const int ntb = 2 * qb + 2;           // block's K-tile count
  const int tend = (qw0 + 31) >> 6;     // this wave's last (masked) tile

  // staging geometry: thread covers 16B of row rs (8 threads/row, coalesced);
  // source col pre-swizzled by the same XOR the reads use (involution)
  const int rs = tid >> 3;
  const int swoff = (((tid & 7) << 4) ^ ((rs & 7) << 4)) >> 1;   // elems

  int cur = 0;
  STAGE(0, 0);
  __syncthreads();

  for (int t = 0; t < ntb; ++t) {
    if (t + 1 < ntb) STAGE(cur ^ 1, t + 1);
    if (t <= tend) COMPT(t, t == tend);
    __syncthreads();                    // drains vmcnt+lgkmcnt: tile t+1 landed,
    cur ^= 1;                           // buffer cur free for overwrite
  }

  // epilogue: O^T regs -> O[b][q][h*64 + d], d = 32*dsub + 8a + 4H + {0..3}
  const float rl = 1.0f / l;
  unsigned short* ob = Og + (size_t)(bS + qg) * 1024 + h64 + 4 * H;
#pragma unroll
  for (int a2 = 0; a2 < 4; ++a2) {
    uint2v w01, w23;
    w01.x = cvtpk(o0[4 * a2 + 0] * rl, o0[4 * a2 + 1] * rl);
    w01.y = cvtpk(o0[4 * a2 + 2] * rl, o0[4 * a2 + 3] * rl);
    w23.x = cvtpk(o1[4 * a2 + 0] * rl, o1[4 * a2 + 1] * rl);
    w23.y = cvtpk(o1[4 * a2 + 2] * rl, o1[4 * a2 + 3] * rl);
    *(uint2v*)(ob + 8 * a2) = w01;
    *(uint2v*)(ob + 32 + 8 * a2) = w23;
  }
}

// ----------------------------------------------------------------- launch ---
extern "C" void kernel_launch(void* const* d_in, const int* in_sizes, int n_in,
                              void* d_out, int out_size, void* d_ws, size_t ws_size,
                              hipStream_t stream) {
  const float* x = (const float*)d_in[0];
  const float* Wq = (const float*)d_in[1];
  const float* Wk = (const float*)d_in[2];
  const float* Wv = (const float*)d_in[3];
  const float* Wo = (const float*)d_in[4];

  unsigned short* xb = (unsigned short*)d_ws;          // 4194304
  unsigned short* Wqb = xb + 4194304;                  // 1048576 each
  unsigned short* Wkb = Wqb + 1048576;
  unsigned short* Wvb = Wkb + 1048576;
  unsigned short* Wob = Wvb + 1048576;
  unsigned short* Qb = Wob + 1048576;                  // 4194304 each
  unsigned short* Kb = Qb + 4194304;
  unsigned short* Vtb = Kb + 4194304;
  unsigned short* Ob = Vtb + 4194304;

  cvt_bf16<<<4096, 256, 0, stream>>>(x, xb, 1048576);
  cvt_w4<<<dim3(1024, 4), 256, 0, stream>>>(Wq, Wk, Wv, Wo, Wqb, Wkb, Wvb, Wob, 262144);

  gemm_qkv<<<dim3(8, 32, 3), 256, 0, stream>>>(xb, Wqb, Wkb, Wvb, Qb, Kb, Vtb);

  attn_fwd<<<512, 256, 0, stream>>>(Qb, Kb, Vtb, Ob);

  gemm_out<<<dim3(8, 32), 256, 0, stream>>>(Ob, Wob, (float*)d_out);
}